// Round 1
// baseline (162.106 us; speedup 1.0000x reference)
//
#include <hip/hip_runtime.h>
#include <math.h>

#define BLK 256
#define CH 4
#define LPB (BLK*CH)   // 1024 elements per block

// ---------------------------------------------------------------------------
// Workspace pointer bundle (all float arrays, laid out in d_ws)
// ---------------------------------------------------------------------------
struct WsPtrs {
  float *F00,*F01,*F10,*F11,*Q00,*Q01,*Q11;   // model, N each
  float *nat1,*nat2,*qm,*qv;                  // EP state, N each
  float *mf0,*mf1,*Pf00,*Pf01,*Pf11;          // filtered, N each
  float *tup;    // scan tuples, comp stride N (filter uses 14 comps, smoother 9)
  float *tpref;  // per-thread exclusive prefixes, comp stride N/CH
  float *agg;    // block aggregates, comp stride G
  float *bpref;  // block exclusive prefixes, comp stride G
};

// Gauss-Hermite (physicists') nodes/weights, deg 20
__device__ const double GHX[20] = {
 -5.387480890011233, -4.603682449550744, -3.944764040115625, -3.347854567383216,
 -2.788806058428131, -2.254974002089276, -1.738537712116586, -1.234076215395323,
 -0.7374737285453944, -0.2453407083009012, 0.2453407083009012, 0.7374737285453944,
  1.234076215395323,  1.738537712116586,  2.254974002089276,  2.788806058428131,
  3.347854567383216,  3.944764040115625,  4.603682449550744,  5.387480890011233 };
__device__ const double GHW[20] = {
 2.229393645534151e-13, 4.399340992273176e-10, 1.086069370769281e-07, 7.802556478532063e-06,
 2.283386360163528e-04, 3.243773342237862e-03, 2.481052088746361e-02, 1.090172060200233e-01,
 2.866755053628341e-01, 4.622436696006101e-01, 4.622436696006101e-01, 2.866755053628341e-01,
 1.090172060200233e-01, 2.481052088746361e-02, 3.243773342237862e-03, 2.283386360163528e-04,
 7.802556478532063e-06, 1.086069370769281e-07, 4.399340992273176e-10, 2.229393645534151e-13 };

#define SQRT2      1.4142135623730951
#define INV_SQRTPI 0.5641895835477563

// ---------------------------------------------------------------------------
// Filtering scan element: [0..3]=A, [4..5]=b, [6..8]=C(00,01,11),
//                         [9..10]=eta, [11..13]=J(00,01,11)
// combine(a = earlier range, b = later range)  (Sarkka & Garcia-Fernandez)
// ---------------------------------------------------------------------------
__device__ __forceinline__ void comb_f(const double* a, const double* b, double* o){
  const double Aa00=a[0],Aa01=a[1],Aa10=a[2],Aa11=a[3];
  const double ba0=a[4],ba1=a[5];
  const double Ca00=a[6],Ca01=a[7],Ca11=a[8];
  const double ea0=a[9],ea1=a[10];
  const double Ja00=a[11],Ja01=a[12],Ja11=a[13];
  const double Ab00=b[0],Ab01=b[1],Ab10=b[2],Ab11=b[3];
  const double bb0=b[4],bb1=b[5];
  const double Cb00=b[6],Cb01=b[7],Cb11=b[8];
  const double eb0=b[9],eb1=b[10];
  const double Jb00=b[11],Jb01=b[12],Jb11=b[13];

  // M = (I + C_a J_b)^-1
  const double T00 = 1.0 + Ca00*Jb00 + Ca01*Jb01;
  const double T01 =       Ca00*Jb01 + Ca01*Jb11;
  const double T10 =       Ca01*Jb00 + Ca11*Jb01;
  const double T11 = 1.0 + Ca01*Jb01 + Ca11*Jb11;
  const double idet = 1.0/(T00*T11 - T01*T10);
  const double M00 =  T11*idet, M01 = -T01*idet, M10 = -T10*idet, M11 = T00*idet;
  // P = A_b * M
  const double P00 = Ab00*M00 + Ab01*M10, P01 = Ab00*M01 + Ab01*M11;
  const double P10 = Ab10*M00 + Ab11*M10, P11 = Ab10*M01 + Ab11*M11;
  // A_out = P * A_a
  o[0] = P00*Aa00 + P01*Aa10;
  o[1] = P00*Aa01 + P01*Aa11;
  o[2] = P10*Aa00 + P11*Aa10;
  o[3] = P10*Aa01 + P11*Aa11;
  // b_out = P*(b_a + C_a eta_b) + b_b
  const double u0 = ba0 + Ca00*eb0 + Ca01*eb1;
  const double u1 = ba1 + Ca01*eb0 + Ca11*eb1;
  o[4] = P00*u0 + P01*u1 + bb0;
  o[5] = P10*u0 + P11*u1 + bb1;
  // C_out = P*C_a*A_b^T + C_b
  const double W00 = P00*Ca00 + P01*Ca01, W01 = P00*Ca01 + P01*Ca11;
  const double W10 = P10*Ca00 + P11*Ca01, W11 = P10*Ca01 + P11*Ca11;
  o[6] = W00*Ab00 + W01*Ab01 + Cb00;
  o[7] = W00*Ab10 + W01*Ab11 + Cb01;
  o[8] = W10*Ab10 + W11*Ab11 + Cb11;
  // eta_out = A_a^T * M^T * (eta_b - J_b b_a) + eta_a
  const double v0 = eb0 - (Jb00*ba0 + Jb01*ba1);
  const double v1 = eb1 - (Jb01*ba0 + Jb11*ba1);
  const double Nv0 = M00*v0 + M10*v1;
  const double Nv1 = M01*v0 + M11*v1;
  o[9]  = Aa00*Nv0 + Aa10*Nv1 + ea0;
  o[10] = Aa01*Nv0 + Aa11*Nv1 + ea1;
  // J_out = A_a^T * (M^T J_b) * A_a + J_a
  const double X00 = M00*Jb00 + M10*Jb01, X01 = M00*Jb01 + M10*Jb11;
  const double X10 = M01*Jb00 + M11*Jb01, X11 = M01*Jb01 + M11*Jb11;
  const double Y00 = Aa00*X00 + Aa10*X10, Y01 = Aa00*X01 + Aa10*X11;
  const double Y10 = Aa01*X00 + Aa11*X10, Y11 = Aa01*X01 + Aa11*X11;
  o[11] = Y00*Aa00 + Y01*Aa10 + Ja00;
  o[12] = Y00*Aa01 + Y01*Aa11 + Ja01;
  o[13] = Y10*Aa01 + Y11*Aa11 + Ja11;
}

// Smoother element: [0..3]=E, [4..5]=g, [6..8]=L(00,01,11)
// Reversed-scan combine: a = prefix (covers larger k), b = new elem (smaller k)
// result = b (x) a : E = E_b E_a ; g = E_b g_a + g_b ; L = E_b L_a E_b^T + L_b
__device__ __forceinline__ void comb_s(const double* a, const double* b, double* o){
  const double Ea00=a[0],Ea01=a[1],Ea10=a[2],Ea11=a[3];
  const double ga0=a[4],ga1=a[5];
  const double La00=a[6],La01=a[7],La11=a[8];
  const double Eb00=b[0],Eb01=b[1],Eb10=b[2],Eb11=b[3];
  const double gb0=b[4],gb1=b[5];
  const double Lb00=b[6],Lb01=b[7],Lb11=b[8];

  o[0] = Eb00*Ea00 + Eb01*Ea10;
  o[1] = Eb00*Ea01 + Eb01*Ea11;
  o[2] = Eb10*Ea00 + Eb11*Ea10;
  o[3] = Eb10*Ea01 + Eb11*Ea11;
  o[4] = Eb00*ga0 + Eb01*ga1 + gb0;
  o[5] = Eb10*ga0 + Eb11*ga1 + gb1;
  const double W00 = Eb00*La00 + Eb01*La01, W01 = Eb00*La01 + Eb01*La11;
  const double W10 = Eb10*La00 + Eb11*La01, W11 = Eb10*La01 + Eb11*La11;
  o[6] = W00*Eb00 + W01*Eb01 + Lb00;
  o[7] = W00*Eb10 + W01*Eb11 + Lb01;
  o[8] = W10*Eb10 + W11*Eb11 + Lb11;
}

// ---------------------------------------------------------------------------
// Model build: A (F), Q per step (analytic cancellation-free forms, f64)
// ---------------------------------------------------------------------------
__global__ void model_kernel(const float* times, const float* ll, const float* lv,
                             WsPtrs ws, int N){
  const int i = blockIdx.x*blockDim.x + threadIdx.x;
  if (i >= N) return;
  const double lam = sqrt(3.0)/exp((double)ll[0]);
  const double s2  = exp((double)lv[0]);
  const double dt  = (i==0) ? 0.0 : ((double)times[i] - (double)times[i-1]);
  const double ld  = lam*dt;
  const double e   = exp(-ld);
  const double F00 = e*(1.0+ld), F01 = e*dt, F10 = -lam*lam*dt*e, F11 = e*(1.0-ld);
  const double e2  = e*e;
  const double q00 = s2*(1.0 - e2*((1.0+ld)*(1.0+ld) + ld*ld));
  const double q01 = 2.0*s2*lam*e2*ld*ld;
  const double q11 = lam*lam*s2*(1.0 - e2*(ld*ld + (1.0-ld)*(1.0-ld)));
  ws.F00[i]=(float)F00; ws.F01[i]=(float)F01; ws.F10[i]=(float)F10; ws.F11[i]=(float)F11;
  ws.Q00[i]=(float)q00; ws.Q01[i]=(float)q01; ws.Q11[i]=(float)q11;
}

// ---------------------------------------------------------------------------
// EP site update (Gauss-Hermite, Poisson): writes nat1, nat2
// ---------------------------------------------------------------------------
__global__ void site_kernel(const int* y, WsPtrs ws, int N, int iter){
  const int i = blockIdx.x*blockDim.x + threadIdx.x;
  if (i >= N) return;
  double qm, qv, n1, n2;
  if (iter == 0){ qm = 0.0; qv = 1.0; n1 = 0.0; n2 = 1e-6; }
  else { qm = (double)ws.qm[i]; qv = (double)ws.qv[i];
         n1 = (double)ws.nat1[i]; n2 = (double)ws.nat2[i]; }
  const double cp = fmax(1.0/qv - n2, 1e-6);
  const double cv = 1.0/cp;
  const double cm = cv*(qm/qv - n1);
  const double s  = sqrt(cv);
  double Ee = 0.0;
  #pragma unroll
  for (int k=0;k<20;k++)
    Ee += (GHW[k]*INV_SQRTPI)*exp(cm + s*(SQRT2*GHX[k]));
  const double nprec = fmax(Ee, 1e-6);
  const double nn1 = ((double)y[i] - Ee) + nprec*cm;
  n1 = 0.5*n1 + 0.5*nn1;
  n2 = fmax(0.5*n2 + 0.5*nprec, 1e-6);
  ws.nat1[i]=(float)n1; ws.nat2[i]=(float)n2;
}

// ---------------------------------------------------------------------------
// Filter element construction
// ---------------------------------------------------------------------------
__device__ __forceinline__ void build_felem(int idx,
    double F00,double F01,double F10,double F11,
    double q00,double q01,double q11, double n1, double n2,
    double sigma2, double lam, double* e)
{
  const double R = 1.0/n2;
  const double y = n1*R;
  if (idx == 0){
    // prior N(0, P_inf) propagated through A=I,Q=0 then updated
    const double S  = sigma2 + R;
    const double K0 = sigma2/S;
    e[0]=0.0;e[1]=0.0;e[2]=0.0;e[3]=0.0;
    e[4]=K0*y; e[5]=0.0;
    e[6]=sigma2 - K0*sigma2; e[7]=0.0; e[8]=lam*lam*sigma2;
    e[9]=0.0;e[10]=0.0;e[11]=0.0;e[12]=0.0;e[13]=0.0;
  } else {
    const double S = q00 + R, iS = 1.0/S;
    const double K0 = q00*iS, K1 = q01*iS;
    const double om = 1.0 - K0;
    const double yiS = y*iS;
    e[0]=om*F00; e[1]=om*F01;
    e[2]=F10 - K1*F00; e[3]=F11 - K1*F01;
    e[4]=K0*y; e[5]=K1*y;
    e[6]=om*q00; e[7]=om*q01; e[8]=q11 - K1*q01;
    e[9]=yiS*F00; e[10]=yiS*F01;
    e[11]=iS*F00*F00; e[12]=iS*F00*F01; e[13]=iS*F01*F01;
  }
}

// ---------------------------------------------------------------------------
// Filter scan phase 1: chunk partials + block scan of thread aggregates
// ---------------------------------------------------------------------------
__global__ __launch_bounds__(BLK) void filt_phase1(WsPtrs ws, int N,
                                                   const float* ll, const float* lv){
  __shared__ double lds[14][BLK];
  const int t = threadIdx.x, blk = blockIdx.x;
  const int base = blk*LPB + t*CH;
  const int NT = N/CH, G = gridDim.x;
  const double sigma2 = exp((double)lv[0]);
  const double lam = sqrt(3.0)/exp((double)ll[0]);

  const float4 f00 = *(const float4*)(ws.F00+base);
  const float4 f01 = *(const float4*)(ws.F01+base);
  const float4 f10 = *(const float4*)(ws.F10+base);
  const float4 f11 = *(const float4*)(ws.F11+base);
  const float4 q00 = *(const float4*)(ws.Q00+base);
  const float4 q01 = *(const float4*)(ws.Q01+base);
  const float4 q11 = *(const float4*)(ws.Q11+base);
  const float4 n1v = *(const float4*)(ws.nat1+base);
  const float4 n2v = *(const float4*)(ws.nat2+base);

  double acc[14];
  float part[CH][14];
  #pragma unroll
  for (int c=0;c<CH;c++){
    double e[14];
    build_felem(base+c,
      (double)((const float*)&f00)[c], (double)((const float*)&f01)[c],
      (double)((const float*)&f10)[c], (double)((const float*)&f11)[c],
      (double)((const float*)&q00)[c], (double)((const float*)&q01)[c],
      (double)((const float*)&q11)[c],
      (double)((const float*)&n1v)[c], (double)((const float*)&n2v)[c],
      sigma2, lam, e);
    if (c==0){
      #pragma unroll
      for (int i=0;i<14;i++) acc[i]=e[i];
    } else {
      double tmp[14];
      comb_f(acc, e, tmp);
      #pragma unroll
      for (int i=0;i<14;i++) acc[i]=tmp[i];
    }
    #pragma unroll
    for (int i=0;i<14;i++) part[c][i]=(float)acc[i];
  }

  #pragma unroll
  for (int i=0;i<14;i++) lds[i][t]=acc[i];
  __syncthreads();
  for (int d=1; d<BLK; d<<=1){
    double pre[14];
    const bool has = (t >= d);
    if (has){
      #pragma unroll
      for (int i=0;i<14;i++) pre[i]=lds[i][t-d];
    }
    __syncthreads();
    if (has){
      double tmp[14];
      comb_f(pre, acc, tmp);
      #pragma unroll
      for (int i=0;i<14;i++){ acc[i]=tmp[i]; lds[i][t]=acc[i]; }
    }
    __syncthreads();
  }

  // per-thread exclusive prefix
  const int tpix = blk*BLK + t;
  if (t == 0){
    ws.tpref[0*NT+tpix]=1.f; ws.tpref[1*NT+tpix]=0.f;
    ws.tpref[2*NT+tpix]=0.f; ws.tpref[3*NT+tpix]=1.f;
    #pragma unroll
    for (int i=4;i<14;i++) ws.tpref[i*NT+tpix]=0.f;
  } else {
    #pragma unroll
    for (int i=0;i<14;i++) ws.tpref[i*NT+tpix]=(float)lds[i][t-1];
  }
  if (t == BLK-1){
    #pragma unroll
    for (int i=0;i<14;i++) ws.agg[i*G+blk]=(float)acc[i];
  }
  #pragma unroll
  for (int i=0;i<14;i++){
    float4 s; s.x=part[0][i]; s.y=part[1][i]; s.z=part[2][i]; s.w=part[3][i];
    *(float4*)(ws.tup + (size_t)i*N + base) = s;
  }
}

// Filter scan phase 2: scan G block aggregates -> exclusive block prefixes
__global__ void filt_phase2(WsPtrs ws, int G){
  __shared__ double lds[14][256];
  const int t = threadIdx.x;
  double acc[14];
  #pragma unroll
  for (int i=0;i<14;i++){ const double v=(double)ws.agg[i*G+t]; acc[i]=v; lds[i][t]=v; }
  __syncthreads();
  for (int d=1; d<G; d<<=1){
    double pre[14];
    const bool has = (t >= d);
    if (has){
      #pragma unroll
      for (int i=0;i<14;i++) pre[i]=lds[i][t-d];
    }
    __syncthreads();
    if (has){
      double tmp[14];
      comb_f(pre, acc, tmp);
      #pragma unroll
      for (int i=0;i<14;i++){ acc[i]=tmp[i]; lds[i][t]=acc[i]; }
    }
    __syncthreads();
  }
  if (t == 0){
    ws.bpref[0*G+t]=1.f; ws.bpref[1*G+t]=0.f; ws.bpref[2*G+t]=0.f; ws.bpref[3*G+t]=1.f;
    #pragma unroll
    for (int i=4;i<14;i++) ws.bpref[i*G+t]=0.f;
  } else {
    #pragma unroll
    for (int i=0;i<14;i++) ws.bpref[i*G+t]=(float)lds[i][t-1];
  }
}

// Filter scan phase 3: apply prefixes, emit filtered mean/cov
__global__ __launch_bounds__(BLK) void filt_phase3(WsPtrs ws, int N){
  const int t = threadIdx.x, blk = blockIdx.x;
  const int base = blk*LPB + t*CH;
  const int NT = N/CH, G = gridDim.x;
  double bp[14], tp[14], pre[14];
  #pragma unroll
  for (int i=0;i<14;i++) bp[i]=(double)ws.bpref[i*G+blk];
  const int tpix = blk*BLK + t;
  #pragma unroll
  for (int i=0;i<14;i++) tp[i]=(double)ws.tpref[i*NT+tpix];
  comb_f(bp, tp, pre);

  float4 pv[14];
  #pragma unroll
  for (int i=0;i<14;i++) pv[i]=*(const float4*)(ws.tup + (size_t)i*N + base);

  float4 om0, om1, op00, op01, op11;
  #pragma unroll
  for (int c=0;c<CH;c++){
    double e[14], r[14];
    #pragma unroll
    for (int i=0;i<14;i++) e[i]=(double)((const float*)&pv[i])[c];
    comb_f(pre, e, r);
    ((float*)&om0)[c]=(float)r[4];
    ((float*)&om1)[c]=(float)r[5];
    ((float*)&op00)[c]=(float)r[6];
    ((float*)&op01)[c]=(float)r[7];
    ((float*)&op11)[c]=(float)r[8];
  }
  *(float4*)(ws.mf0 +base)=om0;
  *(float4*)(ws.mf1 +base)=om1;
  *(float4*)(ws.Pf00+base)=op00;
  *(float4*)(ws.Pf01+base)=op01;
  *(float4*)(ws.Pf11+base)=op11;
}

// ---------------------------------------------------------------------------
// Smoother element construction (k < N-1); k == N-1 handled by caller
// ---------------------------------------------------------------------------
__device__ __forceinline__ void build_selem(
    double mf0,double mf1, double Pf00,double Pf01,double Pf11,
    double F00,double F01,double F10,double F11,
    double q00,double q01,double q11, double* e)
{
  const double mp0 = F00*mf0 + F01*mf1;
  const double mp1 = F10*mf0 + F11*mf1;
  const double W00 = F00*Pf00 + F01*Pf01, W01 = F00*Pf01 + F01*Pf11;
  const double W10 = F10*Pf00 + F11*Pf01, W11 = F10*Pf01 + F11*Pf11;
  const double Pp00 = W00*F00 + W01*F01 + q00;
  const double Pp01 = W00*F10 + W01*F11 + q01;
  const double Pp11 = W10*F10 + W11*F11 + q11;
  const double idet = 1.0/(Pp00*Pp11 - Pp01*Pp01);
  const double i00 = Pp11*idet, i01 = -Pp01*idet, i11 = Pp00*idet;
  const double U00 = Pf00*F00 + Pf01*F01, U01 = Pf00*F10 + Pf01*F11;
  const double U10 = Pf01*F00 + Pf11*F01, U11 = Pf01*F10 + Pf11*F11;
  const double E00 = U00*i00 + U01*i01, E01 = U00*i01 + U01*i11;
  const double E10 = U10*i00 + U11*i01, E11 = U10*i01 + U11*i11;
  e[0]=E00; e[1]=E01; e[2]=E10; e[3]=E11;
  e[4] = mf0 - (E00*mp0 + E01*mp1);
  e[5] = mf1 - (E10*mp0 + E11*mp1);
  const double Z00 = E00*Pp00 + E01*Pp01, Z01 = E00*Pp01 + E01*Pp11;
  const double Z10 = E10*Pp00 + E11*Pp01, Z11 = E10*Pp01 + E11*Pp11;
  e[6] = Pf00 - (Z00*E00 + Z01*E01);
  e[7] = Pf01 - (Z00*E10 + Z01*E11);
  e[8] = Pf11 - (Z10*E10 + Z11*E11);
}

// Smoother phase 1 (reversed scan: scan index j -> original k = N-1-j)
__global__ __launch_bounds__(BLK) void sm_phase1(WsPtrs ws, int N){
  __shared__ double lds[9][BLK];
  const int t = threadIdx.x, blk = blockIdx.x;
  const int base = blk*LPB + t*CH;
  const int NT = N/CH, G = gridDim.x;
  const int kb = N - 4 - base;   // this thread's elements: k = kb+3 .. kb

  const float4 m0v  = *(const float4*)(ws.mf0 +kb);
  const float4 m1v  = *(const float4*)(ws.mf1 +kb);
  const float4 p00v = *(const float4*)(ws.Pf00+kb);
  const float4 p01v = *(const float4*)(ws.Pf01+kb);
  const float4 p11v = *(const float4*)(ws.Pf11+kb);

  double acc[9];
  float part[CH][9];
  #pragma unroll
  for (int c=0;c<CH;c++){
    const int k  = N-1-(base+c);
    const int ci = 3-c;
    double e[9];
    const double mf0 =(double)((const float*)&m0v )[ci];
    const double mf1 =(double)((const float*)&m1v )[ci];
    const double Pf00=(double)((const float*)&p00v)[ci];
    const double Pf01=(double)((const float*)&p01v)[ci];
    const double Pf11=(double)((const float*)&p11v)[ci];
    if (k == N-1){
      e[0]=0.0;e[1]=0.0;e[2]=0.0;e[3]=0.0;
      e[4]=mf0; e[5]=mf1; e[6]=Pf00; e[7]=Pf01; e[8]=Pf11;
    } else {
      const double F00=(double)ws.F00[k+1], F01=(double)ws.F01[k+1];
      const double F10=(double)ws.F10[k+1], F11=(double)ws.F11[k+1];
      const double q00=(double)ws.Q00[k+1], q01=(double)ws.Q01[k+1];
      const double q11=(double)ws.Q11[k+1];
      build_selem(mf0,mf1,Pf00,Pf01,Pf11, F00,F01,F10,F11, q00,q01,q11, e);
    }
    if (c==0){
      #pragma unroll
      for (int i=0;i<9;i++) acc[i]=e[i];
    } else {
      double tmp[9];
      comb_s(acc, e, tmp);
      #pragma unroll
      for (int i=0;i<9;i++) acc[i]=tmp[i];
    }
    #pragma unroll
    for (int i=0;i<9;i++) part[c][i]=(float)acc[i];
  }

  #pragma unroll
  for (int i=0;i<9;i++) lds[i][t]=acc[i];
  __syncthreads();
  for (int d=1; d<BLK; d<<=1){
    double pre[9];
    const bool has = (t >= d);
    if (has){
      #pragma unroll
      for (int i=0;i<9;i++) pre[i]=lds[i][t-d];
    }
    __syncthreads();
    if (has){
      double tmp[9];
      comb_s(pre, acc, tmp);
      #pragma unroll
      for (int i=0;i<9;i++){ acc[i]=tmp[i]; lds[i][t]=acc[i]; }
    }
    __syncthreads();
  }

  const int tpix = blk*BLK + t;
  if (t == 0){
    ws.tpref[0*NT+tpix]=1.f; ws.tpref[1*NT+tpix]=0.f;
    ws.tpref[2*NT+tpix]=0.f; ws.tpref[3*NT+tpix]=1.f;
    #pragma unroll
    for (int i=4;i<9;i++) ws.tpref[i*NT+tpix]=0.f;
  } else {
    #pragma unroll
    for (int i=0;i<9;i++) ws.tpref[i*NT+tpix]=(float)lds[i][t-1];
  }
  if (t == BLK-1){
    #pragma unroll
    for (int i=0;i<9;i++) ws.agg[i*G+blk]=(float)acc[i];
  }
  #pragma unroll
  for (int i=0;i<9;i++){
    float4 s; s.x=part[0][i]; s.y=part[1][i]; s.z=part[2][i]; s.w=part[3][i];
    *(float4*)(ws.tup + (size_t)i*N + base) = s;
  }
}

__global__ void sm_phase2(WsPtrs ws, int G){
  __shared__ double lds[9][256];
  const int t = threadIdx.x;
  double acc[9];
  #pragma unroll
  for (int i=0;i<9;i++){ const double v=(double)ws.agg[i*G+t]; acc[i]=v; lds[i][t]=v; }
  __syncthreads();
  for (int d=1; d<G; d<<=1){
    double pre[9];
    const bool has = (t >= d);
    if (has){
      #pragma unroll
      for (int i=0;i<9;i++) pre[i]=lds[i][t-d];
    }
    __syncthreads();
    if (has){
      double tmp[9];
      comb_s(pre, acc, tmp);
      #pragma unroll
      for (int i=0;i<9;i++){ acc[i]=tmp[i]; lds[i][t]=acc[i]; }
    }
    __syncthreads();
  }
  if (t == 0){
    ws.bpref[0*G+t]=1.f; ws.bpref[1*G+t]=0.f; ws.bpref[2*G+t]=0.f; ws.bpref[3*G+t]=1.f;
    #pragma unroll
    for (int i=4;i<9;i++) ws.bpref[i*G+t]=0.f;
  } else {
    #pragma unroll
    for (int i=0;i<9;i++) ws.bpref[i*G+t]=(float)lds[i][t-1];
  }
}

__global__ __launch_bounds__(BLK) void sm_phase3(WsPtrs ws, int N, float* out, int write_out){
  const int t = threadIdx.x, blk = blockIdx.x;
  const int base = blk*LPB + t*CH;
  const int NT = N/CH, G = gridDim.x;
  const int kb = N - 4 - base;
  double bp[9], tp[9], pre[9];
  #pragma unroll
  for (int i=0;i<9;i++) bp[i]=(double)ws.bpref[i*G+blk];
  const int tpix = blk*BLK + t;
  #pragma unroll
  for (int i=0;i<9;i++) tp[i]=(double)ws.tpref[i*NT+tpix];
  comb_s(bp, tp, pre);

  float4 pv[9];
  #pragma unroll
  for (int i=0;i<9;i++) pv[i]=*(const float4*)(ws.tup + (size_t)i*N + base);

  float4 oqm, oqv;
  #pragma unroll
  for (int c=0;c<CH;c++){
    double e[9], r[9];
    #pragma unroll
    for (int i=0;i<9;i++) e[i]=(double)((const float*)&pv[i])[c];
    comb_s(pre, e, r);
    const int ci = 3-c;   // element c is original index k = kb + 3-c
    ((float*)&oqm)[ci]=(float)r[4];
    ((float*)&oqv)[ci]=fmaxf((float)r[6], 1e-12f);
  }
  *(float4*)(ws.qm+kb)=oqm;
  *(float4*)(ws.qv+kb)=oqv;
  if (write_out) *(float4*)(out+kb)=oqm;
}

// ---------------------------------------------------------------------------
extern "C" void kernel_launch(void* const* d_in, const int* in_sizes, int n_in,
                              void* d_out, int out_size, void* d_ws, size_t ws_size,
                              hipStream_t stream) {
  (void)n_in; (void)out_size; (void)ws_size;
  const int N = in_sizes[0];                 // 131072, multiple of LPB
  const float* times = (const float*)d_in[0];
  const int*   y     = (const int*)d_in[1];
  const float* ll    = (const float*)d_in[2];
  const float* lv    = (const float*)d_in[3];
  float* out = (float*)d_out;

  const int G = N / LPB;                     // 128 blocks
  float* w = (float*)d_ws;
  const size_t n = (size_t)N;
  WsPtrs ws;
  ws.F00=w;        ws.F01=w+n;     ws.F10=w+2*n;  ws.F11=w+3*n;
  ws.Q00=w+4*n;    ws.Q01=w+5*n;   ws.Q11=w+6*n;
  ws.nat1=w+7*n;   ws.nat2=w+8*n;  ws.qm=w+9*n;   ws.qv=w+10*n;
  ws.mf0=w+11*n;   ws.mf1=w+12*n;
  ws.Pf00=w+13*n;  ws.Pf01=w+14*n; ws.Pf11=w+15*n;
  ws.tup=w+16*n;                   // 14*N
  ws.tpref=w+30*n;                 // 14*(N/CH)
  ws.agg  = w + 30*n + 14*(n/CH);  // 14*G
  ws.bpref= ws.agg + 14*(size_t)G; // 14*G

  const int EB = 256, EG = (N+EB-1)/EB;
  model_kernel<<<EG, EB, 0, stream>>>(times, ll, lv, ws, N);
  for (int it=0; it<4; ++it){
    site_kernel<<<EG, EB, 0, stream>>>(y, ws, N, it);
    filt_phase1<<<G, BLK, 0, stream>>>(ws, N, ll, lv);
    filt_phase2<<<1, G, 0, stream>>>(ws, G);
    filt_phase3<<<G, BLK, 0, stream>>>(ws, N);
    sm_phase1<<<G, BLK, 0, stream>>>(ws, N);
    sm_phase2<<<1, G, 0, stream>>>(ws, G);
    sm_phase3<<<G, BLK, 0, stream>>>(ws, N, out, (it==3) ? 1 : 0);
  }
}